// Round 1
// baseline (273.926 us; speedup 1.0000x reference)
//
#include <hip/hip_runtime.h>

#define N_NODES 50000
#define N_EDGES 800000
#define DIN 256
#define DOUT 64
#define LN_EPS 1e-5f

// ---------------- degree count ----------------
__global__ void count_kernel(const int* __restrict__ ei, int* __restrict__ cnt) {
    int e = blockIdx.x * blockDim.x + threadIdx.x;
    if (e < N_EDGES) {
        int d = ei[N_EDGES + e];   // dst row
        atomicAdd(&cnt[d], 1);
    }
}

// ---------------- exclusive scan (offsets) + dinv ----------------
// single block, 1024 threads, loops over N in chunks of 1024
__global__ void scan_kernel(const int* __restrict__ cnt, int* __restrict__ offs,
                            float* __restrict__ dinv) {
    __shared__ int wsum[16];
    __shared__ int carry_s;
    const int tid = threadIdx.x;
    const int lane = tid & 63, wid = tid >> 6;
    if (tid == 0) { carry_s = 0; offs[0] = 0; }
    __syncthreads();
    for (int base = 0; base < N_NODES; base += 1024) {
        int i = base + tid;
        int v = (i < N_NODES) ? cnt[i] : 0;
        int s = v;
        #pragma unroll
        for (int d = 1; d < 64; d <<= 1) {
            int t = __shfl_up(s, d, 64);
            if (lane >= d) s += t;
        }
        if (lane == 63) wsum[wid] = s;
        __syncthreads();
        if (tid < 16) {
            int x = wsum[tid];
            #pragma unroll
            for (int d = 1; d < 16; d <<= 1) {
                int t = __shfl_up(x, d, 64);
                if (tid >= d) x += t;
            }
            wsum[tid] = x;   // inclusive scan of wave totals
        }
        __syncthreads();
        int incl = carry_s + ((wid == 0) ? 0 : wsum[wid - 1]) + s;
        if (i < N_NODES) {
            offs[i + 1] = incl;
            dinv[i] = rsqrtf((float)(v + 1));  // +1 self loop; deg>=1 always
        }
        __syncthreads();
        if (tid == 1023) carry_s = incl;   // chunk-padded lanes add 0, so this is chunk total
        __syncthreads();
    }
}

// ---------------- CSR fill ----------------
__global__ void fill_kernel(const int* __restrict__ ei, const int* __restrict__ offs,
                            int* __restrict__ cursor, int* __restrict__ csr) {
    int e = blockIdx.x * blockDim.x + threadIdx.x;
    if (e < N_EDGES) {
        int s = ei[e];
        int d = ei[N_EDGES + e];
        int pos = atomicAdd(&cursor[d], 1);
        csr[offs[d] + pos] = s;
    }
}

// ---------------- GEMM: h[n][d] = sum_k xs[n][k] * W[d][k] ----------------
// 256 threads = 4 waves; each wave does 4 rows, lane d = output feature d.
// W (64KB) staged in LDS with XOR swizzle: row r element c stored at r*64 + (c ^ (r&7))
// (float4 units) -> 64-lane read of column k spreads over all 8 bank groups.
__global__ __launch_bounds__(256) void gemm_kernel(const float* __restrict__ xs,
                                                   const float* __restrict__ W,
                                                   float* __restrict__ h) {
    __shared__ float4 wl[64 * 64];   // 64KB
    const int tid = threadIdx.x;
    const float4* w4 = (const float4*)W;
    #pragma unroll
    for (int i = 0; i < 16; ++i) {
        int j = tid + i * 256;           // 0..4095
        int row = j >> 6, col = j & 63;
        wl[row * 64 + (col ^ (row & 7))] = w4[j];
    }
    __syncthreads();
    const int lane = tid & 63, wv = tid >> 6;
    int n0 = blockIdx.x * 16 + wv * 4;
    if (n0 >= N_NODES) return;
    float acc0 = 0.f, acc1 = 0.f, acc2 = 0.f, acc3 = 0.f;
    const float4* x0 = (const float4*)(xs + (size_t)n0 * DIN);
    const int swz = lane & 7;
    const float4* wrow = wl + lane * 64;
    #pragma unroll 8
    for (int k = 0; k < 64; ++k) {
        float4 w_ = wrow[k ^ swz];
        float4 a0 = x0[k];
        float4 a1 = x0[64 + k];
        float4 a2 = x0[128 + k];
        float4 a3 = x0[192 + k];
        acc0 += a0.x * w_.x + a0.y * w_.y + a0.z * w_.z + a0.w * w_.w;
        acc1 += a1.x * w_.x + a1.y * w_.y + a1.z * w_.z + a1.w * w_.w;
        acc2 += a2.x * w_.x + a2.y * w_.y + a2.z * w_.z + a2.w * w_.w;
        acc3 += a3.x * w_.x + a3.y * w_.y + a3.z * w_.z + a3.w * w_.w;
    }
    h[(size_t)(n0 + 0) * DOUT + lane] = acc0;
    h[(size_t)(n0 + 1) * DOUT + lane] = acc1;
    h[(size_t)(n0 + 2) * DOUT + lane] = acc2;
    h[(size_t)(n0 + 3) * DOUT + lane] = acc3;
}

// ---------------- gather + bias + LayerNorm ----------------
// one wave per node; lane d = feature d.
__global__ __launch_bounds__(256) void gather_ln_kernel(
    const float* __restrict__ h, const int* __restrict__ offs, const int* __restrict__ csr,
    const float* __restrict__ dinv, const float* __restrict__ bias,
    const float* __restrict__ gamma, const float* __restrict__ beta,
    float* __restrict__ out) {
    int node = blockIdx.x * 4 + (threadIdx.x >> 6);
    if (node >= N_NODES) return;
    int lane = threadIdx.x & 63;
    float di = dinv[node];
    float acc = h[(size_t)node * DOUT + lane] * di;  // self loop (x di again below)
    int start = offs[node], end = offs[node + 1];
    for (int c = start; c < end; c += 64) {
        int m = min(64, end - c);
        int sv = (lane < m) ? csr[c + lane] : 0;
        float dv = (lane < m) ? dinv[sv] : 0.0f;
        int j = 0;
        for (; j + 4 <= m; j += 4) {
            int s0 = __shfl(sv, j, 64);     float w0 = __shfl(dv, j, 64);
            int s1 = __shfl(sv, j + 1, 64); float w1 = __shfl(dv, j + 1, 64);
            int s2 = __shfl(sv, j + 2, 64); float w2 = __shfl(dv, j + 2, 64);
            int s3 = __shfl(sv, j + 3, 64); float w3 = __shfl(dv, j + 3, 64);
            float h0 = h[(size_t)s0 * DOUT + lane];
            float h1 = h[(size_t)s1 * DOUT + lane];
            float h2 = h[(size_t)s2 * DOUT + lane];
            float h3 = h[(size_t)s3 * DOUT + lane];
            acc = fmaf(h0, w0, acc);
            acc = fmaf(h1, w1, acc);
            acc = fmaf(h2, w2, acc);
            acc = fmaf(h3, w3, acc);
        }
        for (; j < m; ++j) {
            int s0 = __shfl(sv, j, 64); float w0 = __shfl(dv, j, 64);
            acc = fmaf(h[(size_t)s0 * DOUT + lane], w0, acc);
        }
    }
    acc = acc * di + bias[lane];
    // LayerNorm over 64 features (one wave)
    float sum = acc;
    #pragma unroll
    for (int d = 1; d < 64; d <<= 1) sum += __shfl_xor(sum, d, 64);
    float mu = sum * (1.0f / 64.0f);
    float diff = acc - mu;
    float vs = diff * diff;
    #pragma unroll
    for (int d = 1; d < 64; d <<= 1) vs += __shfl_xor(vs, d, 64);
    float var = vs * (1.0f / 64.0f);
    float r = rsqrtf(var + LN_EPS);
    out[(size_t)node * DOUT + lane] = diff * r * gamma[lane] + beta[lane];
}

extern "C" void kernel_launch(void* const* d_in, const int* in_sizes, int n_in,
                              void* d_out, int out_size, void* d_ws, size_t ws_size,
                              hipStream_t stream) {
    const float* xs    = (const float*)d_in[0];
    const int*   ei    = (const int*)d_in[1];
    const float* W     = (const float*)d_in[2];
    const float* bias  = (const float*)d_in[3];
    const float* gamma = (const float*)d_in[4];
    const float* beta  = (const float*)d_in[5];
    float* out = (float*)d_out;

    char* base = (char*)d_ws;
    auto align_up = [](size_t x) { return (x + 255) & ~(size_t)255; };
    size_t o = 0;
    int* cnt    = (int*)(base + o);   o = align_up(o + (size_t)N_NODES * 4);
    int* cursor = (int*)(base + o);   o = align_up(o + (size_t)N_NODES * 4);
    size_t zero_bytes = o;            // cnt + cursor regions
    int* offs   = (int*)(base + o);   o = align_up(o + (size_t)(N_NODES + 1) * 4);
    float* dinv = (float*)(base + o); o = align_up(o + (size_t)N_NODES * 4);
    int* csr    = (int*)(base + o);   o = align_up(o + (size_t)N_EDGES * 4);
    float* h    = (float*)(base + o); o += (size_t)N_NODES * DOUT * 4;
    (void)ws_size; (void)in_sizes; (void)n_in; (void)out_size;

    hipMemsetAsync(d_ws, 0, zero_bytes, stream);
    count_kernel<<<(N_EDGES + 255) / 256, 256, 0, stream>>>(ei, cnt);
    gemm_kernel<<<(N_NODES + 15) / 16, 256, 0, stream>>>(xs, W, h);
    scan_kernel<<<1, 1024, 0, stream>>>(cnt, offs, dinv);
    fill_kernel<<<(N_EDGES + 255) / 256, 256, 0, stream>>>(ei, offs, cursor, csr);
    gather_ln_kernel<<<(N_NODES + 3) / 4, 256, 0, stream>>>(h, offs, csr, dinv,
                                                            bias, gamma, beta, out);
}